// Round 2
// baseline (33714.850 us; speedup 1.0000x reference)
//
#include <hip/hip_runtime.h>
#include <cstdint>
#include <cstddef>

#define FEAT 256
#define HWPX 16384
#define NDIR 10000
#define NCLS 4          // classes 1..4
#define BCAP 4096       // per-class column capacity for B (n_c ~ 3277)
#define NSWEEP 9
#define NBLK_FP 157     // ceil(NDIR/64)

// ---- workspace layout (element offsets; 4B elements) ----
static const size_t OFF_FEATT = 0;                                // 16384*256 f32
static const size_t OFF_IDX   = OFF_FEATT + (size_t)HWPX*FEAT;    // 4*16384 int
static const size_t OFF_CNT   = OFF_IDX + (size_t)NCLS*HWPX;      // 4 int (+pad)
static const size_t OFF_MIU   = OFF_CNT + 64;                     // 4*256 f32
static const size_t OFF_MIUP  = OFF_MIU + (size_t)NCLS*FEAT;      // 32*4*256 f32 partials
static const size_t OFF_G     = OFF_MIUP + (size_t)32*NCLS*FEAT;  // 4*65536 f32
static const size_t OFF_ETS   = OFF_G + (size_t)NCLS*FEAT*FEAT;   // 4*65536 f32
static const size_t OFF_EVAL  = OFF_ETS + (size_t)NCLS*FEAT*FEAT; // 4*256 f32
static const size_t OFF_LPART = OFF_EVAL + (size_t)NCLS*FEAT;     // 4*160*2 f32 per-block partials
static const size_t OFF_B     = OFF_LPART + (size_t)NCLS*160*2;   // 4*256*BCAP f32
// total ~ 37 MB

// ---------------- transpose feat (256 x 16384) -> featT (16384 x 256) ----------------
__global__ __launch_bounds__(256) void k_transpose(const float* __restrict__ feat, float* __restrict__ ws){
  __shared__ float tile[32][33];
  float* featT = ws + OFF_FEATT;
  int j0 = blockIdx.x*32, f0 = blockIdx.y*32;
  int tx = threadIdx.x, ty = threadIdx.y; // (32, 8)
  #pragma unroll
  for (int r=0;r<4;r++){
    int f = f0 + ty + r*8;
    tile[ty+r*8][tx] = feat[(size_t)f*HWPX + j0 + tx];
  }
  __syncthreads();
  #pragma unroll
  for (int r=0;r<4;r++){
    int j = j0 + ty + r*8;
    featT[(size_t)j*FEAT + f0 + tx] = tile[tx][ty+r*8];
  }
}

// ---------------- build compacted per-class index lists + counts ----------------
__global__ __launch_bounds__(256) void k_index(const int* __restrict__ lab, float* ws){
  __shared__ int sc[256];
  int* idx = (int*)(ws + OFF_IDX);
  int* cnt = (int*)(ws + OFF_CNT);
  int t = threadIdx.x;
  int base = t*64;
  for (int c=1;c<=NCLS;c++){
    __syncthreads();
    int m = 0;
    for (int k=0;k<64;k++) m += (lab[base+k]==c) ? 1 : 0;
    sc[t] = m;
    __syncthreads();
    for (int off=1; off<256; off<<=1){
      int v = (t>=off)? sc[t-off] : 0;
      __syncthreads();
      sc[t] += v;
      __syncthreads();
    }
    int pos = sc[t] - m;
    if (t==255) cnt[c-1] = sc[255];
    int* ic = idx + (size_t)(c-1)*HWPX;
    for (int k=0;k<64;k++){
      if (lab[base+k]==c) ic[pos++] = base+k;
    }
  }
}

// ---------------- per-class feature-sum partials (deterministic, no atomics) ----------------
__global__ __launch_bounds__(256) void k_miu_part(const int* __restrict__ lab, float* ws){
  const float* featT = ws + OFF_FEATT;
  float* part = ws + OFF_MIUP;
  int f = threadIdx.x;
  int b = blockIdx.x;
  int j0 = b*512;
  float a0=0.f,a1=0.f,a2=0.f,a3=0.f;
  for (int j=j0;j<j0+512;j++){
    float v = featT[(size_t)j*FEAT + f];
    int c = lab[j];
    a0 += (c==1)? v : 0.f;
    a1 += (c==2)? v : 0.f;
    a2 += (c==3)? v : 0.f;
    a3 += (c==4)? v : 0.f;
  }
  float* pb = part + (size_t)b*NCLS*FEAT;
  pb[0*FEAT+f] = a0;
  pb[1*FEAT+f] = a1;
  pb[2*FEAT+f] = a2;
  pb[3*FEAT+f] = a3;
}

__global__ __launch_bounds__(1024) void k_miu_fin(float* ws){
  int t = threadIdx.x;            // 0..1023 = c*FEAT+f
  int c = t / FEAT;
  const float* part = ws + OFF_MIUP;
  float s = 0.f;
  for (int b=0;b<32;b++) s += part[(size_t)b*NCLS*FEAT + t];   // fixed order
  int n = ((int*)(ws+OFF_CNT))[c];
  float nf = fmaxf((float)n, 1.f);
  ws[OFF_MIU + t] = s / nf;
}

// ---------------- cov per class (64x64 tiles): G = m2mat/n - miu miu^T + eps I ----------------
__global__ __launch_bounds__(256) void k_cov(float* ws){
  __shared__ float Xa[32][68];
  __shared__ float Xb[32][68];
  const float* featT = ws + OFF_FEATT;
  int c = blockIdx.y;
  const int* idx = (const int*)(ws + OFF_IDX) + (size_t)c*HWPX;
  int n = ((int*)(ws+OFF_CNT))[c];
  float nf = fmaxf((float)n,1.f);
  const float* miu = ws + OFF_MIU + (size_t)c*FEAT;
  float* G = ws + OFF_G + (size_t)c*FEAT*FEAT;
  int fb = (blockIdx.x & 3)*64, gb = (blockIdx.x >> 2)*64;
  int t = threadIdx.x;
  int ti = t & 15, tj = t >> 4;
  float acc[4][4] = {};
  int jr = t >> 3;         // 0..31
  int s8 = (t & 7) * 8;    // 0..56
  int nch = (n + 31)/32;
  for (int ch=0; ch<nch; ch++){
    int jg = ch*32 + jr;
    __syncthreads();
    if (jg < n){
      int jx = idx[jg];
      const float* row = featT + (size_t)jx*FEAT;
      #pragma unroll
      for (int k=0;k<8;k++){ Xa[jr][s8+k] = row[fb+s8+k]; Xb[jr][s8+k] = row[gb+s8+k]; }
    } else {
      #pragma unroll
      for (int k=0;k<8;k++){ Xa[jr][s8+k] = 0.f; Xb[jr][s8+k] = 0.f; }
    }
    __syncthreads();
    for (int jj=0;jj<32;jj++){
      float4 av = *(const float4*)&Xa[jj][ti*4];
      float4 bv = *(const float4*)&Xb[jj][tj*4];
      float aa[4] = {av.x,av.y,av.z,av.w};
      float bb[4] = {bv.x,bv.y,bv.z,bv.w};
      #pragma unroll
      for (int ii=0; ii<4; ii++)
        #pragma unroll
        for (int j2=0; j2<4; j2++)
          acc[ii][j2] += aa[ii]*bb[j2];
    }
  }
  float eps = fminf(fmaxf(1e-5f/nf, 1e-8f), 1e-5f);
  #pragma unroll
  for (int ii=0; ii<4; ii++){
    #pragma unroll
    for (int j2=0; j2<4; j2++){
      int f = fb + ti*4 + ii, g = gb + tj*4 + j2;
      float v = acc[ii][j2]/nf - miu[f]*miu[g] + ((f==g)? eps : 0.f);
      G[(size_t)g*FEAT + f] = v;   // column-major, col g
    }
  }
}

// ---------------- one-sided cyclic Jacobi eigensolver (per class block) ----------------
__global__ __launch_bounds__(1024) void k_jacobi(float* ws){
  __shared__ float colsq[256];
  __shared__ int srt[256];
  int c = blockIdx.x;
  float* G = ws + OFF_G + (size_t)c*FEAT*FEAT;
  int t = threadIdx.x;
  int pid = t >> 3, ln = t & 7;

  for (int sw=0; sw<NSWEEP; sw++){
    __syncthreads();
    if (t < 256){
      const float* col = G + (size_t)t*FEAT;
      float s = 0.f;
      for (int f=0; f<FEAT; f+=4){
        float4 v = *(const float4*)&col[f];
        s += v.x*v.x + v.y*v.y + v.z*v.z + v.w*v.w;
      }
      colsq[t] = s;
    }
    for (int r=0; r<255; r++){
      __syncthreads();
      int p, q;
      if (pid == 0){ p = 255; q = r; }
      else {
        p = (r + pid) % 255;
        q = (r + 255 - pid) % 255;
      }
      float* Cp = G + (size_t)p*FEAT + ln*32;
      float* Cq = G + (size_t)q*FEAT + ln*32;
      float4 vp[8], vq[8];
      double dd = 0.0;
      #pragma unroll
      for (int k=0;k<8;k++){
        vp[k] = *(const float4*)&Cp[k*4];
        vq[k] = *(const float4*)&Cq[k*4];
        dd += (double)vp[k].x*(double)vq[k].x + (double)vp[k].y*(double)vq[k].y
            + (double)vp[k].z*(double)vq[k].z + (double)vp[k].w*(double)vq[k].w;
      }
      dd += __shfl_xor(dd, 1);
      dd += __shfl_xor(dd, 2);
      dd += __shfl_xor(dd, 4);
      float app = colsq[p], aqq = colsq[q];
      // skip below ~1e-6 relative off-diagonal (fp32 column noise floor)
      if (dd*dd > (double)app*(double)aqq*1e-12){
        double tau = ((double)aqq - (double)app) / (2.0*dd);
        double tt = (tau >= 0.0 ? 1.0 : -1.0) / (fabs(tau) + sqrt(1.0 + tau*tau));
        double ccd = 1.0 / sqrt(1.0 + tt*tt);
        double ssd = tt*ccd;
        float cc = (float)ccd, ssn = (float)ssd;
        #pragma unroll
        for (int k=0;k<8;k++){
          float4 np, nq;
          np.x = cc*vp[k].x - ssn*vq[k].x;  nq.x = ssn*vp[k].x + cc*vq[k].x;
          np.y = cc*vp[k].y - ssn*vq[k].y;  nq.y = ssn*vp[k].y + cc*vq[k].y;
          np.z = cc*vp[k].z - ssn*vq[k].z;  nq.z = ssn*vp[k].z + cc*vq[k].z;
          np.w = cc*vp[k].w - ssn*vq[k].w;  nq.w = ssn*vp[k].w + cc*vq[k].w;
          *(float4*)&Cp[k*4] = np;
          *(float4*)&Cq[k*4] = nq;
        }
        if (ln == 0){
          double a2 = ccd*ccd*(double)app - 2.0*ccd*ssd*dd + ssd*ssd*(double)aqq;
          double q2 = ssd*ssd*(double)app + 2.0*ccd*ssd*dd + ccd*ccd*(double)aqq;
          colsq[p] = (float)a2;
          colsq[q] = (float)q2;
        }
      }
    }
  }
  // exact column norms, then rank-sort descending
  __syncthreads();
  if (t < 256){
    const float* col = G + (size_t)t*FEAT;
    float s = 0.f;
    for (int f=0; f<FEAT; f+=4){
      float4 v = *(const float4*)&col[f];
      s += v.x*v.x + v.y*v.y + v.z*v.z + v.w*v.w;
    }
    colsq[t] = s;
  }
  __syncthreads();
  if (t < 256){
    float my = colsq[t];
    int rk = 0;
    for (int u=0; u<256; u++){
      float cu = colsq[u];
      rk += ((cu > my) || (cu == my && u < t)) ? 1 : 0;
    }
    srt[rk] = t;
  }
  __syncthreads();
  float* evals = ws + OFF_EVAL + (size_t)c*FEAT;
  float* Et = ws + OFF_ETS + (size_t)c*FEAT*FEAT;
  if (t < 256) evals[t] = sqrtf(colsq[srt[t]]);
  int k = t >> 2, sg = (t & 3)*64;
  int scol = srt[k];
  float lam = sqrtf(colsq[scol]);
  float inv = 1.f / lam;
  const float* col = G + (size_t)scol*FEAT;
  for (int f=sg; f<sg+64; f+=4){
    float4 v = *(const float4*)&col[f];
    v.x*=inv; v.y*=inv; v.z*=inv; v.w*=inv;
    *(float4*)&Et[(size_t)k*FEAT + f] = v;
  }
}

// ---------------- B[c] = EtS (256x256, sorted) @ centered_gathered (256 x n_c) ----------------
__global__ __launch_bounds__(256) void k_bmat(float* ws){
  __shared__ float Ae[256][68];   // [f][k-local]
  __shared__ float Bc[256][68];   // [f][j-local]
  int c = blockIdx.z;
  int n = ((int*)(ws+OFF_CNT))[c];
  int j0 = blockIdx.x*64;
  if (j0 >= n) return;            // block-uniform
  int kb = blockIdx.y*64;
  const float* featT = ws + OFF_FEATT;
  const int* idx = (const int*)(ws + OFF_IDX) + (size_t)c*HWPX;
  const float* miu = ws + OFF_MIU + (size_t)c*FEAT;
  const float* Ets = ws + OFF_ETS + (size_t)c*FEAT*FEAT;
  float* Bg = ws + OFF_B + (size_t)c*FEAT*BCAP;
  int t = threadIdx.x;
  int l4 = t >> 2, sgf = (t & 3)*64;
  // stage Ae
  {
    const float* Erow = Ets + (size_t)(kb+l4)*FEAT + sgf;
    for (int f=0; f<64; f+=4){
      float4 v = *(const float4*)&Erow[f];
      Ae[sgf+f+0][l4] = v.x; Ae[sgf+f+1][l4] = v.y;
      Ae[sgf+f+2][l4] = v.z; Ae[sgf+f+3][l4] = v.w;
    }
  }
  // stage Bc (centered gathered columns)
  {
    int jg = j0 + l4;
    if (jg < n){
      const float* Frow = featT + (size_t)idx[jg]*FEAT + sgf;
      const float* mp = miu + sgf;
      for (int f=0; f<64; f+=4){
        float4 v = *(const float4*)&Frow[f];
        Bc[sgf+f+0][l4] = v.x - mp[f+0];
        Bc[sgf+f+1][l4] = v.y - mp[f+1];
        Bc[sgf+f+2][l4] = v.z - mp[f+2];
        Bc[sgf+f+3][l4] = v.w - mp[f+3];
      }
    } else {
      for (int f=0; f<64; f++) Bc[sgf+f][l4] = 0.f;
    }
  }
  __syncthreads();
  int ti = t & 15, tj = t >> 4;   // ti: k-sub, tj: j-sub
  float acc[4][4] = {};
  for (int f=0; f<FEAT; f+=4){
    #pragma unroll
    for (int ff=0; ff<4; ff++){
      float4 av = *(const float4*)&Ae[f+ff][ti*4];
      float4 bv = *(const float4*)&Bc[f+ff][tj*4];
      float aa[4] = {av.x,av.y,av.z,av.w};
      float bb[4] = {bv.x,bv.y,bv.z,bv.w};
      #pragma unroll
      for (int kk=0;kk<4;kk++)
        #pragma unroll
        for (int jj=0;jj<4;jj++)
          acc[kk][jj] += aa[kk]*bb[jj];
    }
  }
  #pragma unroll
  for (int kk=0; kk<4; kk++){
    float4 o; o.x=acc[kk][0]; o.y=acc[kk][1]; o.z=acc[kk][2]; o.w=acc[kk][3];
    *(float4*)&Bg[(size_t)(kb + ti*4 + kk)*BCAP + j0 + tj*4] = o;
  }
}

// ---------------- fp GEMM (pm @ B) with fused m2/m4 + per-block loss partials ----------------
__global__ __launch_bounds__(256) void k_fp(const float* __restrict__ pm, float* ws){
  __shared__ float As[256][68];   // [k][i-local]  (pm tile, transposed)
  __shared__ float Bs[256][68];   // [k][j-local]
  __shared__ float ev[256];
  __shared__ float red[64][17];
  __shared__ float m2s[64];
  __shared__ float m4s[64];
  int c = blockIdx.y;
  int i0 = blockIdx.x*64;
  int n = ((int*)(ws+OFF_CNT))[c];
  float nf = fmaxf((float)n, 1.f);
  const float* evals = ws + OFF_EVAL + (size_t)c*FEAT;
  const float* Bg = ws + OFF_B + (size_t)c*FEAT*BCAP;
  int t = threadIdx.x;
  int l4 = t >> 2;
  // stage As
  {
    int sgf = (t & 3)*64;
    int gi = i0 + l4;
    if (gi < NDIR){
      const float* row = pm + (size_t)gi*FEAT + sgf;
      for (int f=0; f<64; f+=4){
        float4 v = *(const float4*)&row[f];
        As[sgf+f+0][l4] = v.x; As[sgf+f+1][l4] = v.y;
        As[sgf+f+2][l4] = v.z; As[sgf+f+3][l4] = v.w;
      }
    } else {
      for (int f=0; f<64; f++) As[sgf+f][l4] = 0.f;
    }
  }
  if (t < 256) ev[t] = evals[t];
  int ti = t & 15, tj = t >> 4;
  float s2[4] = {0.f,0.f,0.f,0.f};
  float s4[4] = {0.f,0.f,0.f,0.f};
  int nch = (n + 63)/64;
  int sgj = (t & 3)*16;
  for (int ch=0; ch<nch; ch++){
    int j0 = ch*64;
    __syncthreads();
    for (int g=0; g<4; g++){
      int r = l4 + 64*g;
      const float* Brow = Bg + (size_t)r*BCAP + j0 + sgj;
      #pragma unroll
      for (int e=0; e<16; e+=4){
        int j = j0 + sgj + e;
        float4 v;
        if (j + 3 < n) v = *(const float4*)&Brow[e];
        else {
          v.x = (j+0<n)? Brow[e+0] : 0.f;
          v.y = (j+1<n)? Brow[e+1] : 0.f;
          v.z = (j+2<n)? Brow[e+2] : 0.f;
          v.w = (j+3<n)? Brow[e+3] : 0.f;
        }
        *(float4*)&Bs[r][sgj+e] = v;
      }
    }
    __syncthreads();
    float acc[4][4] = {};
    for (int k=0; k<FEAT; k+=4){
      #pragma unroll
      for (int kk=0; kk<4; kk++){
        float4 av = *(const float4*)&As[k+kk][ti*4];
        float4 bv = *(const float4*)&Bs[k+kk][tj*4];
        float aa[4] = {av.x,av.y,av.z,av.w};
        float bb[4] = {bv.x,bv.y,bv.z,bv.w};
        #pragma unroll
        for (int ii=0;ii<4;ii++)
          #pragma unroll
          for (int jj=0;jj<4;jj++)
            acc[ii][jj] += aa[ii]*bb[jj];
      }
    }
    #pragma unroll
    for (int ii=0;ii<4;ii++){
      #pragma unroll
      for (int jj=0;jj<4;jj++){
        float v = acc[ii][jj];
        float v2 = v*v;
        s2[ii] += v2;
        s4[ii] += v2*v2;
      }
    }
  }
  __syncthreads();
  #pragma unroll
  for (int ii=0;ii<4;ii++) red[ti*4+ii][tj] = s2[ii];
  __syncthreads();
  if (t < 64){
    float s = 0.f;
    for (int u=0;u<16;u++) s += red[t][u];
    m2s[t] = s;
  }
  __syncthreads();
  #pragma unroll
  for (int ii=0;ii<4;ii++) red[ti*4+ii][tj] = s4[ii];
  __syncthreads();
  if (t < 64){
    float s = 0.f;
    for (int u=0;u<16;u++) s += red[t][u];
    m4s[t] = s;
  }
  __syncthreads();
  if (t < 64){
    float stds = 0.f;
    for (int k=0;k<FEAT;k++){
      float a = As[k][t];
      stds += a*a*ev[k];
    }
    int i = i0 + t;
    float l2 = 0.f, lk = 0.f;
    if (i < NDIR){
      float m2 = m2s[t]/(nf*stds);
      float m4 = m4s[t]/(nf*stds*stds);
      float d2 = m2 - 1.f;
      l2 = d2*d2;
      float dk = m4 - 3.f*m2*m2;
      lk = dk*dk;
    }
    #pragma unroll
    for (int o=1;o<64;o<<=1){
      l2 += __shfl_xor(l2, o);
      lk += __shfl_xor(lk, o);
    }
    if (t == 0){
      float* lp = ws + OFF_LPART + ((size_t)c*160 + blockIdx.x)*2;
      lp[0] = l2;
      lp[1] = lk;
    }
  }
}

// ---------------- final scalar (deterministic fixed-order reduction) ----------------
__global__ __launch_bounds__(64) void k_final(float* ws, float* out){
  int t = threadIdx.x;   // one wave
  const int* cnt = (const int*)(ws + OFF_CNT);
  const float* lp = ws + OFF_LPART;
  float tot = 0.f, an = 0.f;
  for (int c=0;c<NCLS;c++){
    float s2 = 0.f, sk = 0.f;
    for (int b=t; b<NBLK_FP; b+=64){
      s2 += lp[((size_t)c*160 + b)*2 + 0];
      sk += lp[((size_t)c*160 + b)*2 + 1];
    }
    #pragma unroll
    for (int o=1;o<64;o<<=1){
      s2 += __shfl_xor(s2, o);
      sk += __shfl_xor(sk, o);
    }
    if (cnt[c] > 0){
      tot += s2/(float)NDIR + sk/(float)NDIR;
      an += 1.f;
    }
  }
  if (t == 0) out[0] = tot / fmaxf(an, 1.f);
}

extern "C" void kernel_launch(void* const* d_in, const int* in_sizes, int n_in,
                              void* d_out, int out_size, void* d_ws, size_t ws_size,
                              hipStream_t stream) {
  const float* feat = (const float*)d_in[0];
  const int*   lab  = (const int*)d_in[1];
  const float* pm   = (const float*)d_in[2];
  float* out = (float*)d_out;
  float* ws  = (float*)d_ws;

  hipLaunchKernelGGL(k_transpose, dim3(HWPX/32, FEAT/32), dim3(32,8), 0, stream, feat, ws);
  hipLaunchKernelGGL(k_index,     dim3(1),            dim3(256),     0, stream, lab, ws);
  hipLaunchKernelGGL(k_miu_part,  dim3(32),           dim3(256),     0, stream, lab, ws);
  hipLaunchKernelGGL(k_miu_fin,   dim3(1),            dim3(1024),    0, stream, ws);
  hipLaunchKernelGGL(k_cov,       dim3(16, NCLS),     dim3(256),     0, stream, ws);
  hipLaunchKernelGGL(k_jacobi,    dim3(NCLS),         dim3(1024),    0, stream, ws);
  hipLaunchKernelGGL(k_bmat,      dim3(BCAP/64, 4, NCLS), dim3(256), 0, stream, ws);
  hipLaunchKernelGGL(k_fp,        dim3(NBLK_FP, NCLS), dim3(256),    0, stream, pm, ws);
  hipLaunchKernelGGL(k_final,     dim3(1),            dim3(64),      0, stream, ws, out);
}